// Round 11
// baseline (167.438 us; speedup 1.0000x reference)
//
#include <hip/hip_runtime.h>
#include <hip/hip_bf16.h>

#define NN   4096
#define FIN  512
#define NH   4
#define DD   64

typedef float f32x4 __attribute__((ext_vector_type(4)));
typedef short s16x8 __attribute__((ext_vector_type(8)));
typedef int   i32x4 __attribute__((ext_vector_type(4)));

// manual RNE float->bf16
__device__ __forceinline__ short bfbits(float f) {
  union { float f; unsigned u; } v; v.f = f;
  unsigned r = v.u + 0x7FFFu + ((v.u >> 16) & 1u);
  return (short)(r >> 16);
}

// packed pair float->bf16
__device__ __forceinline__ int pkbf(float a, float b) {
  union { float f; unsigned u; } va, vb;
  va.f = a; vb.f = b;
  unsigned ra = (va.u + 0x7FFFu + ((va.u >> 16) & 1u)) >> 16;
  unsigned rb = (vb.u + 0x7FFFu + ((vb.u >> 16) & 1u)) & 0xFFFF0000u;
  return (int)(ra | rb);
}

__device__ __forceinline__ float hexp2(float x) {
#if __has_builtin(__builtin_amdgcn_exp2f)
  return __builtin_amdgcn_exp2f(x);
#else
  return __builtin_exp2f(x);
#endif
}

__device__ __forceinline__ i32x4 ntload4(const int* p) {
  return __builtin_nontemporal_load((const i32x4*)p);
}

// ---------------------------------------------------------------------------
// Fused pre-kernel: grid 768 = 512 pack + 256 k1, interleaved 2:1.
//  pack: vectorized per-lane bit-pack. Thread t packs 2 u32 words (32 cols
//  each) via 16 int4 NON-TEMPORAL loads — pure BW, no ballots, no L2
//  pollution. 8 rows/block.
//  k1: LDS-staged bf16 MFMA; writes tiled V2 + scaled s_src/s_dst.
// ---------------------------------------------------------------------------
__global__ __launch_bounds__(512, 4) void gat_pre(
    const int* __restrict__ adj, const float* __restrict__ x,
    const float* __restrict__ W, const float* __restrict__ a,
    unsigned* __restrict__ bits, short* __restrict__ V2,
    float* __restrict__ ssrc, float* __restrict__ sdst)
{
  __shared__ __align__(16) char sm[34816];
  short* As = (short*)sm;
  short* Bs = (short*)(sm + 17408);
  float* Cs = (float*)sm;

  const int b = blockIdx.x;
  const int t = threadIdx.x;
  const int w = t >> 6, lane = t & 63;

  const int g3 = b / 3, m3 = b - g3 * 3;
  if (m3 < 2) {
    // ---------------- pack (vectorized) ----------------
    const int pb   = g3 * 2 + m3;          // 0..511
    const int row  = (pb << 3) | (t >> 6); // 8 rows/block
    const int w0   = t & 63;               // first word index
    const int* arow = adj + (size_t)row * NN;
#pragma unroll
    for (int ws2 = 0; ws2 < 2; ++ws2) {
      const int wd = w0 + ws2 * 64;        // word 0..127
      const int* cp = arow + wd * 32;
      unsigned word = 0;
#pragma unroll
      for (int i = 0; i < 8; ++i) {
        i32x4 v = ntload4(cp + i * 4);
        word |= ((unsigned)v.x) << (i * 4 + 0);
        word |= ((unsigned)v.y) << (i * 4 + 1);
        word |= ((unsigned)v.z) << (i * 4 + 2);
        word |= ((unsigned)v.w) << (i * 4 + 3);
      }
      bits[(size_t)row * 128 + wd] = word;
    }
    return;
  }

  // ---------------- k1 ----------------
  const int b2 = g3;
  const int h  = b2 >> 6;
  const int r  = b2 & 63;
  const int n0 = r * 64;
  const int lm = lane & 15, q = lane >> 4;
  const int rs = w & 3, cs = w >> 2;

  f32x4 acc[2] = {};
  const float* Wh = W + (size_t)h * (FIN * DD);

  for (int kq = 0; kq < 4; ++kq) {
    {
      const int row = t >> 3, fl = (t & 7) * 16;
      const float* xp = x + (size_t)(n0 + row) * FIN + kq * 128 + fl;
      float4 v0 = ((const float4*)xp)[0];
      float4 v1 = ((const float4*)xp)[1];
      float4 v2 = ((const float4*)xp)[2];
      float4 v3 = ((const float4*)xp)[3];
      union { short s[8]; int4 v; } u0, u1;
      u0.s[0]=bfbits(v0.x); u0.s[1]=bfbits(v0.y); u0.s[2]=bfbits(v0.z); u0.s[3]=bfbits(v0.w);
      u0.s[4]=bfbits(v1.x); u0.s[5]=bfbits(v1.y); u0.s[6]=bfbits(v1.z); u0.s[7]=bfbits(v1.w);
      u1.s[0]=bfbits(v2.x); u1.s[1]=bfbits(v2.y); u1.s[2]=bfbits(v2.z); u1.s[3]=bfbits(v2.w);
      u1.s[4]=bfbits(v3.x); u1.s[5]=bfbits(v3.y); u1.s[6]=bfbits(v3.z); u1.s[7]=bfbits(v3.w);
      *(int4*)(As + row * 136 + fl)     = u0.v;
      *(int4*)(As + row * 136 + fl + 8) = u1.v;
    }
    {
      const int fl = t >> 2, dc = (t & 3) * 16;
      const float* wp = Wh + (size_t)(kq * 128 + fl) * DD + dc;
      float4 w0 = ((const float4*)wp)[0];
      float4 w1 = ((const float4*)wp)[1];
      float4 w2 = ((const float4*)wp)[2];
      float4 w3 = ((const float4*)wp)[3];
      Bs[(dc+ 0)*136+fl]=bfbits(w0.x); Bs[(dc+ 1)*136+fl]=bfbits(w0.y);
      Bs[(dc+ 2)*136+fl]=bfbits(w0.z); Bs[(dc+ 3)*136+fl]=bfbits(w0.w);
      Bs[(dc+ 4)*136+fl]=bfbits(w1.x); Bs[(dc+ 5)*136+fl]=bfbits(w1.y);
      Bs[(dc+ 6)*136+fl]=bfbits(w1.z); Bs[(dc+ 7)*136+fl]=bfbits(w1.w);
      Bs[(dc+ 8)*136+fl]=bfbits(w2.x); Bs[(dc+ 9)*136+fl]=bfbits(w2.y);
      Bs[(dc+10)*136+fl]=bfbits(w2.z); Bs[(dc+11)*136+fl]=bfbits(w2.w);
      Bs[(dc+12)*136+fl]=bfbits(w3.x); Bs[(dc+13)*136+fl]=bfbits(w3.y);
      Bs[(dc+14)*136+fl]=bfbits(w3.z); Bs[(dc+15)*136+fl]=bfbits(w3.w);
    }
    __syncthreads();
#pragma unroll
    for (int s = 0; s < 4; ++s) {
      s16x8 af = *(const s16x8*)(As + (rs * 16 + lm) * 136 + s * 32 + q * 8);
#pragma unroll
      for (int c = 0; c < 2; ++c) {
        s16x8 bf = *(const s16x8*)(Bs + (cs * 32 + c * 16 + lm) * 136 + s * 32 + q * 8);
        acc[c] = __builtin_amdgcn_mfma_f32_16x16x32_bf16(af, bf, acc[c], 0, 0, 0);
      }
    }
    __syncthreads();
  }

#pragma unroll
  for (int c = 0; c < 2; ++c)
#pragma unroll
    for (int g = 0; g < 4; ++g)
      Cs[(cs * 32 + c * 16 + lm) * 65 + (rs * 16 + q * 4 + g)] = acc[c][g];
  __syncthreads();

  {
    const int d = t >> 3, nc = (t & 7) * 8;
    union { short s[8]; int4 v; } u;
#pragma unroll
    for (int e = 0; e < 8; ++e) u.s[e] = bfbits(Cs[d * 65 + nc + e]);
    *(int4*)(V2 + ((size_t)(h * 128 + r * 2 + (nc >> 5)) * 64 + d) * 32 + (nc & 31)) = u.v;
  }
  if (t < 128) {
    const int n = t & 63;
    const int isdst = t >> 6;
    const float* av = a + h * 128 + isdst * 64;
    float s = 0.f;
#pragma unroll 8
    for (int d = 0; d < 64; ++d) s = fmaf(Cs[d * 65 + n], av[d], s);
    const float LOG2E = 1.4426950408889634f;
    (isdst ? sdst : ssrc)[h * NN + n0 + n] = s * LOG2E;
  }
}

// ---------------------------------------------------------------------------
// Kernel 2: barrier-free flash-GAT (r7 structure) + XCD head pinning.
// grid 512: blk = k*8 + c, h = c&3, rt = k*2 + (c>>2) -> with round-robin
// block->XCD dispatch each XCD touches ONE head's V2 (512KB) + half the bits
// (1MB) + sdst (16KB): ~1.5MB, fits per-XCD L2 -> kills the ~10x HBM refetch.
// out stores are non-temporal (never re-read; keeps L2 clean).
// ---------------------------------------------------------------------------
__global__ __launch_bounds__(512, 4) void gat_k2(
    const unsigned* __restrict__ bits, const short* __restrict__ V2,
    const float* __restrict__ ssrc, const float* __restrict__ sdst,
    const float* __restrict__ bias, float* __restrict__ out)
{
  __shared__ float MRG[4][32][68];
  __shared__ float Lm[8][32];

  const int b  = blockIdx.x;
  const int c8 = b & 7;
  const int k  = b >> 3;            // 0..63
  const int h  = c8 & 3;
  const int rt = k * 2 + (c8 >> 2); // 0..127
  const int t  = threadIdx.x;
  const int w  = t >> 6, lane = t & 63;
  const int lm = lane & 15, q = lane >> 4;
  const int jc = w;
  const int ib = rt * 32;
  const int i0 = ib + lm, i1 = i0 + 16;

  const float src0 = ssrc[h * NN + i0] - 1000.0f;
  const float src1 = ssrc[h * NN + i1] - 1000.0f;

  const short one = 0x3F80;
  s16x8 bones = {};
  if (lm == 0) {
    bones[0]=one; bones[1]=one; bones[2]=one; bones[3]=one;
    bones[4]=one; bones[5]=one; bones[6]=one; bones[7]=one;
  }

  f32x4 acc[2][4] = {};
  f32x4 accl[2] = {};

  const short*  Vb  = V2 + (size_t)h * 262144 + (size_t)jc * 16 * 2048
                      + lm * 32 + q * 8;
  const float*  sdh = sdst + h * NN + jc * 512 + q * 8;
  const unsigned* b0 = bits + (size_t)i0 * 128 + jc * 16;
  const unsigned* b1 = bits + (size_t)i1 * 128 + jc * 16;

  unsigned Wd0[4], Wd1[4], nWd0[4], nWd1[4];
  *(uint4*)Wd0 = ((const uint4*)b0)[0];
  *(uint4*)Wd1 = ((const uint4*)b1)[0];

  s16x8 bfc[4];
#pragma unroll
  for (int c = 0; c < 4; ++c) bfc[c] = *(const s16x8*)(Vb + c * 512);
  float4 S0 = ((const float4*)sdh)[0];
  float4 S1 = ((const float4*)(sdh + 4))[0];

  const int shq = q * 8;

  for (int s = 0; s < 4; ++s) {
    if (s < 3) {
      *(uint4*)nWd0 = ((const uint4*)b0)[s + 1];
      *(uint4*)nWd1 = ((const uint4*)b1)[s + 1];
    }
#pragma unroll
    for (int jsub = 0; jsub < 4; ++jsub) {
      const int js = s * 4 + jsub;
      const int jn = (js < 15) ? js + 1 : js;

      s16x8 bfn[4];
#pragma unroll
      for (int c = 0; c < 4; ++c)
        bfn[c] = *(const s16x8*)(Vb + jn * 2048 + c * 512);
      float4 T0 = ((const float4*)(sdh + jn * 32))[0];
      float4 T1 = ((const float4*)(sdh + jn * 32 + 4))[0];

      const unsigned wq0 = Wd0[jsub] >> shq;
      const unsigned wq1 = Wd1[jsub] >> shq;

#pragma unroll
      for (int rf = 0; rf < 2; ++rf) {
        const float src_i = rf ? src1 : src0;
        const unsigned wq = rf ? wq1 : wq0;
        float p[8];
#define PGEN(dv, e)                                                           \
        { float tp = src_i + (dv);                                            \
          float u  = fmaxf(tp, fmaf(tp, 0.2f, -800.0f));                      \
          u = fmaf((float)((wq >> (e)) & 1u), 1000.0f, u);                    \
          p[e] = hexp2(u); }
        PGEN(S0.x, 0) PGEN(S0.y, 1) PGEN(S0.z, 2) PGEN(S0.w, 3)
        PGEN(S1.x, 4) PGEN(S1.y, 5) PGEN(S1.z, 6) PGEN(S1.w, 7)
#undef PGEN
        union { int i4[4]; s16x8 v; } af;
        af.i4[0] = pkbf(p[0], p[1]);
        af.i4[1] = pkbf(p[2], p[3]);
        af.i4[2] = pkbf(p[4], p[5]);
        af.i4[3] = pkbf(p[6], p[7]);
#pragma unroll
        for (int c = 0; c < 4; ++c)
          acc[rf][c] = __builtin_amdgcn_mfma_f32_16x16x32_bf16(af.v, bfc[c], acc[rf][c], 0, 0, 0);
        accl[rf] = __builtin_amdgcn_mfma_f32_16x16x32_bf16(af.v, bones, accl[rf], 0, 0, 0);
      }
#pragma unroll
      for (int c = 0; c < 4; ++c) bfc[c] = bfn[c];
      S0 = T0; S1 = T1;
    }
#pragma unroll
    for (int e = 0; e < 4; ++e) { Wd0[e] = nWd0[e]; Wd1[e] = nWd1[e]; }
  }

  // ---- merge 8 j-chunks (end-of-kernel tree) ----
  if (lm == 0) {
#pragma unroll
    for (int rf = 0; rf < 2; ++rf)
#pragma unroll
      for (int g = 0; g < 4; ++g)
        Lm[w][rf * 16 + q * 4 + g] = accl[rf][g];
  }
  if (w >= 4) {
#pragma unroll
    for (int rf = 0; rf < 2; ++rf)
#pragma unroll
      for (int c = 0; c < 4; ++c)
#pragma unroll
        for (int g = 0; g < 4; ++g)
          MRG[w - 4][rf * 16 + q * 4 + g][c * 16 + lm] = acc[rf][c][g];
  }
  __syncthreads();
  if (w < 4) {
#pragma unroll
    for (int rf = 0; rf < 2; ++rf)
#pragma unroll
      for (int c = 0; c < 4; ++c)
#pragma unroll
        for (int g = 0; g < 4; ++g)
          acc[rf][c][g] += MRG[w][rf * 16 + q * 4 + g][c * 16 + lm];
  }
  __syncthreads();
  if (w >= 1 && w < 4) {
#pragma unroll
    for (int rf = 0; rf < 2; ++rf)
#pragma unroll
      for (int c = 0; c < 4; ++c)
#pragma unroll
        for (int g = 0; g < 4; ++g)
          MRG[w - 1][rf * 16 + q * 4 + g][c * 16 + lm] = acc[rf][c][g];
  }
  __syncthreads();
  if (w == 0) {
#pragma unroll
    for (int rf = 0; rf < 2; ++rf) {
#pragma unroll
      for (int g = 0; g < 4; ++g) {
        const int row = rf * 16 + q * 4 + g;
        float l = 0.f;
#pragma unroll
        for (int ww = 0; ww < 8; ++ww) l += Lm[ww][row];
        const float inv = 1.0f / l;
        const int grow = ib + row;
#pragma unroll
        for (int c = 0; c < 4; ++c) {
          const int col = c * 16 + lm;
          float v = acc[rf][c][g]
                  + MRG[0][row][col] + MRG[1][row][col] + MRG[2][row][col];
          float o = fmaf(v, inv, bias[h * 64 + col]);
          __builtin_nontemporal_store(fmaxf(o, 0.0f),
              out + (size_t)grow * 256 + h * 64 + col);
        }
      }
    }
  }
}

// ---------------------------------------------------------------------------
extern "C" void kernel_launch(void* const* d_in, const int* in_sizes, int n_in,
                              void* d_out, int out_size, void* d_ws, size_t ws_size,
                              hipStream_t stream) {
  const float* x    = (const float*)d_in[0];
  const int*   adj  = (const int*)d_in[1];
  const float* W    = (const float*)d_in[2];
  const float* a    = (const float*)d_in[3];
  const float* bias = (const float*)d_in[4];
  float* out = (float*)d_out;

  // ws: V2 2MB | bits 2MB | ssrc 64KB | sdst 64KB
  short* V2 = (short*)d_ws;
  unsigned* bits = (unsigned*)((char*)d_ws + (size_t)2 * 1024 * 1024);
  float* ssrc = (float*)((char*)d_ws + (size_t)4 * 1024 * 1024);
  float* sdst = ssrc + NH * NN;

  gat_pre<<<768, 512, 0, stream>>>(adj, x, W, a, bits, V2, ssrc, sdst);
  gat_k2<<<512, 512, 0, stream>>>(bits, V2, ssrc, sdst, bias, out);
}

// Round 12
// 138.411 us; speedup vs baseline: 1.2097x; 1.2097x over previous
//
#include <hip/hip_runtime.h>
#include <hip/hip_bf16.h>

#define NN   4096
#define FIN  512
#define NH   4
#define DD   64

typedef float f32x4 __attribute__((ext_vector_type(4)));
typedef short s16x8 __attribute__((ext_vector_type(8)));

// manual RNE float->bf16
__device__ __forceinline__ short bfbits(float f) {
  union { float f; unsigned u; } v; v.f = f;
  unsigned r = v.u + 0x7FFFu + ((v.u >> 16) & 1u);
  return (short)(r >> 16);
}

// packed pair float->bf16
__device__ __forceinline__ int pkbf(float a, float b) {
  union { float f; unsigned u; } va, vb;
  va.f = a; vb.f = b;
  unsigned ra = (va.u + 0x7FFFu + ((va.u >> 16) & 1u)) >> 16;
  unsigned rb = (vb.u + 0x7FFFu + ((vb.u >> 16) & 1u)) & 0xFFFF0000u;
  return (int)(ra | rb);
}

__device__ __forceinline__ float hexp2(float x) {
#if __has_builtin(__builtin_amdgcn_exp2f)
  return __builtin_amdgcn_exp2f(x);
#else
  return __builtin_exp2f(x);
#endif
}

// ---------------------------------------------------------------------------
// Fused pre-kernel: grid 768 = 512 pack + 256 k1, interleaved 2:1.
//  pack: ballot-based bit-pack (r7 form — fully coalesced 256B/wave loads;
//  the r10 NT-vectorized version was latency-bound at 1.5 TB/s, reverted).
//  k1: LDS-staged bf16 MFMA; writes tiled V2 + scaled s_src/s_dst.
// ---------------------------------------------------------------------------
__global__ __launch_bounds__(512, 4) void gat_pre(
    const int* __restrict__ adj, const float* __restrict__ x,
    const float* __restrict__ W, const float* __restrict__ a,
    unsigned long long* __restrict__ bits, short* __restrict__ V2,
    float* __restrict__ ssrc, float* __restrict__ sdst)
{
  __shared__ __align__(16) char sm[34816];
  short* As = (short*)sm;
  short* Bs = (short*)(sm + 17408);
  float* Cs = (float*)sm;

  const int b = blockIdx.x;
  const int t = threadIdx.x;
  const int w = t >> 6, lane = t & 63;

  const int g3 = b / 3, m3 = b - g3 * 3;
  if (m3 < 2) {
    // ---------------- pack (ballot, coalesced) ----------------
    const int pb = g3 * 2 + m3;          // 0..511
    const int rrow = (pb << 3) | w;      // 8 rows/block
    const int* arow = adj + (size_t)rrow * NN;
    unsigned long long mine = 0;
#pragma unroll 8
    for (int it = 0; it < 64; ++it) {
      int v = arow[it * 64 + lane];
      unsigned long long bl = __ballot(v != 0);
      if (lane == it) mine = bl;
    }
    bits[(size_t)rrow * 64 + lane] = mine;
    return;
  }

  // ---------------- k1 ----------------
  const int b2 = g3;
  const int h  = b2 >> 6;
  const int r  = b2 & 63;
  const int n0 = r * 64;
  const int lm = lane & 15, q = lane >> 4;
  const int rs = w & 3, cs = w >> 2;

  f32x4 acc[2] = {};
  const float* Wh = W + (size_t)h * (FIN * DD);

  for (int kq = 0; kq < 4; ++kq) {
    {
      const int row = t >> 3, fl = (t & 7) * 16;
      const float* xp = x + (size_t)(n0 + row) * FIN + kq * 128 + fl;
      float4 v0 = ((const float4*)xp)[0];
      float4 v1 = ((const float4*)xp)[1];
      float4 v2 = ((const float4*)xp)[2];
      float4 v3 = ((const float4*)xp)[3];
      union { short s[8]; int4 v; } u0, u1;
      u0.s[0]=bfbits(v0.x); u0.s[1]=bfbits(v0.y); u0.s[2]=bfbits(v0.z); u0.s[3]=bfbits(v0.w);
      u0.s[4]=bfbits(v1.x); u0.s[5]=bfbits(v1.y); u0.s[6]=bfbits(v1.z); u0.s[7]=bfbits(v1.w);
      u1.s[0]=bfbits(v2.x); u1.s[1]=bfbits(v2.y); u1.s[2]=bfbits(v2.z); u1.s[3]=bfbits(v2.w);
      u1.s[4]=bfbits(v3.x); u1.s[5]=bfbits(v3.y); u1.s[6]=bfbits(v3.z); u1.s[7]=bfbits(v3.w);
      *(int4*)(As + row * 136 + fl)     = u0.v;
      *(int4*)(As + row * 136 + fl + 8) = u1.v;
    }
    {
      const int fl = t >> 2, dc = (t & 3) * 16;
      const float* wp = Wh + (size_t)(kq * 128 + fl) * DD + dc;
      float4 w0 = ((const float4*)wp)[0];
      float4 w1 = ((const float4*)wp)[1];
      float4 w2 = ((const float4*)wp)[2];
      float4 w3 = ((const float4*)wp)[3];
      Bs[(dc+ 0)*136+fl]=bfbits(w0.x); Bs[(dc+ 1)*136+fl]=bfbits(w0.y);
      Bs[(dc+ 2)*136+fl]=bfbits(w0.z); Bs[(dc+ 3)*136+fl]=bfbits(w0.w);
      Bs[(dc+ 4)*136+fl]=bfbits(w1.x); Bs[(dc+ 5)*136+fl]=bfbits(w1.y);
      Bs[(dc+ 6)*136+fl]=bfbits(w1.z); Bs[(dc+ 7)*136+fl]=bfbits(w1.w);
      Bs[(dc+ 8)*136+fl]=bfbits(w2.x); Bs[(dc+ 9)*136+fl]=bfbits(w2.y);
      Bs[(dc+10)*136+fl]=bfbits(w2.z); Bs[(dc+11)*136+fl]=bfbits(w2.w);
      Bs[(dc+12)*136+fl]=bfbits(w3.x); Bs[(dc+13)*136+fl]=bfbits(w3.y);
      Bs[(dc+14)*136+fl]=bfbits(w3.z); Bs[(dc+15)*136+fl]=bfbits(w3.w);
    }
    __syncthreads();
#pragma unroll
    for (int s = 0; s < 4; ++s) {
      s16x8 af = *(const s16x8*)(As + (rs * 16 + lm) * 136 + s * 32 + q * 8);
#pragma unroll
      for (int c = 0; c < 2; ++c) {
        s16x8 bf = *(const s16x8*)(Bs + (cs * 32 + c * 16 + lm) * 136 + s * 32 + q * 8);
        acc[c] = __builtin_amdgcn_mfma_f32_16x16x32_bf16(af, bf, acc[c], 0, 0, 0);
      }
    }
    __syncthreads();
  }

#pragma unroll
  for (int c = 0; c < 2; ++c)
#pragma unroll
    for (int g = 0; g < 4; ++g)
      Cs[(cs * 32 + c * 16 + lm) * 65 + (rs * 16 + q * 4 + g)] = acc[c][g];
  __syncthreads();

  {
    const int d = t >> 3, nc = (t & 7) * 8;
    union { short s[8]; int4 v; } u;
#pragma unroll
    for (int e = 0; e < 8; ++e) u.s[e] = bfbits(Cs[d * 65 + nc + e]);
    *(int4*)(V2 + ((size_t)(h * 128 + r * 2 + (nc >> 5)) * 64 + d) * 32 + (nc & 31)) = u.v;
  }
  if (t < 128) {
    const int n = t & 63;
    const int isdst = t >> 6;
    const float* av = a + h * 128 + isdst * 64;
    float s = 0.f;
#pragma unroll 8
    for (int d = 0; d < 64; ++d) s = fmaf(Cs[d * 65 + n], av[d], s);
    const float LOG2E = 1.4426950408889634f;
    (isdst ? sdst : ssrc)[h * NN + n0 + n] = s * LOG2E;
  }
}

// ---------------------------------------------------------------------------
// Kernel 2: barrier-free flash-GAT + XCD head pinning (r10 structure).
// grid 512: blk = k*8 + c, h = c&3, rt = k*2 + (c>>2) -> with round-robin
// block->XCD dispatch each XCD touches ONE head's V2 (512KB) + half the bits
// (1MB) + sdst (16KB): ~1.5MB, fits per-XCD L2.
// out stores non-temporal (never re-read).
// ---------------------------------------------------------------------------
__global__ __launch_bounds__(512, 4) void gat_k2(
    const unsigned* __restrict__ bits, const short* __restrict__ V2,
    const float* __restrict__ ssrc, const float* __restrict__ sdst,
    const float* __restrict__ bias, float* __restrict__ out)
{
  __shared__ float MRG[4][32][68];
  __shared__ float Lm[8][32];

  const int b  = blockIdx.x;
  const int c8 = b & 7;
  const int k  = b >> 3;            // 0..63
  const int h  = c8 & 3;
  const int rt = k * 2 + (c8 >> 2); // 0..127
  const int t  = threadIdx.x;
  const int w  = t >> 6, lane = t & 63;
  const int lm = lane & 15, q = lane >> 4;
  const int jc = w;
  const int ib = rt * 32;
  const int i0 = ib + lm, i1 = i0 + 16;

  const float src0 = ssrc[h * NN + i0] - 1000.0f;
  const float src1 = ssrc[h * NN + i1] - 1000.0f;

  const short one = 0x3F80;
  s16x8 bones = {};
  if (lm == 0) {
    bones[0]=one; bones[1]=one; bones[2]=one; bones[3]=one;
    bones[4]=one; bones[5]=one; bones[6]=one; bones[7]=one;
  }

  f32x4 acc[2][4] = {};
  f32x4 accl[2] = {};

  const short*  Vb  = V2 + (size_t)h * 262144 + (size_t)jc * 16 * 2048
                      + lm * 32 + q * 8;
  const float*  sdh = sdst + h * NN + jc * 512 + q * 8;
  const unsigned* b0 = bits + (size_t)i0 * 128 + jc * 16;
  const unsigned* b1 = bits + (size_t)i1 * 128 + jc * 16;

  unsigned Wd0[4], Wd1[4], nWd0[4], nWd1[4];
  *(uint4*)Wd0 = ((const uint4*)b0)[0];
  *(uint4*)Wd1 = ((const uint4*)b1)[0];

  s16x8 bfc[4];
#pragma unroll
  for (int c = 0; c < 4; ++c) bfc[c] = *(const s16x8*)(Vb + c * 512);
  float4 S0 = ((const float4*)sdh)[0];
  float4 S1 = ((const float4*)(sdh + 4))[0];

  const int shq = q * 8;

  for (int s = 0; s < 4; ++s) {
    if (s < 3) {
      *(uint4*)nWd0 = ((const uint4*)b0)[s + 1];
      *(uint4*)nWd1 = ((const uint4*)b1)[s + 1];
    }
#pragma unroll
    for (int jsub = 0; jsub < 4; ++jsub) {
      const int js = s * 4 + jsub;
      const int jn = (js < 15) ? js + 1 : js;

      s16x8 bfn[4];
#pragma unroll
      for (int c = 0; c < 4; ++c)
        bfn[c] = *(const s16x8*)(Vb + jn * 2048 + c * 512);
      float4 T0 = ((const float4*)(sdh + jn * 32))[0];
      float4 T1 = ((const float4*)(sdh + jn * 32 + 4))[0];

      const unsigned wq0 = Wd0[jsub] >> shq;
      const unsigned wq1 = Wd1[jsub] >> shq;

#pragma unroll
      for (int rf = 0; rf < 2; ++rf) {
        const float src_i = rf ? src1 : src0;
        const unsigned wq = rf ? wq1 : wq0;
        float p[8];
#define PGEN(dv, e)                                                           \
        { float tp = src_i + (dv);                                            \
          float u  = fmaxf(tp, fmaf(tp, 0.2f, -800.0f));                      \
          u = fmaf((float)((wq >> (e)) & 1u), 1000.0f, u);                    \
          p[e] = hexp2(u); }
        PGEN(S0.x, 0) PGEN(S0.y, 1) PGEN(S0.z, 2) PGEN(S0.w, 3)
        PGEN(S1.x, 4) PGEN(S1.y, 5) PGEN(S1.z, 6) PGEN(S1.w, 7)
#undef PGEN
        union { int i4[4]; s16x8 v; } af;
        af.i4[0] = pkbf(p[0], p[1]);
        af.i4[1] = pkbf(p[2], p[3]);
        af.i4[2] = pkbf(p[4], p[5]);
        af.i4[3] = pkbf(p[6], p[7]);
#pragma unroll
        for (int c = 0; c < 4; ++c)
          acc[rf][c] = __builtin_amdgcn_mfma_f32_16x16x32_bf16(af.v, bfc[c], acc[rf][c], 0, 0, 0);
        accl[rf] = __builtin_amdgcn_mfma_f32_16x16x32_bf16(af.v, bones, accl[rf], 0, 0, 0);
      }
#pragma unroll
      for (int c = 0; c < 4; ++c) bfc[c] = bfn[c];
      S0 = T0; S1 = T1;
    }
#pragma unroll
    for (int e = 0; e < 4; ++e) { Wd0[e] = nWd0[e]; Wd1[e] = nWd1[e]; }
  }

  // ---- merge 8 j-chunks (end-of-kernel tree) ----
  if (lm == 0) {
#pragma unroll
    for (int rf = 0; rf < 2; ++rf)
#pragma unroll
      for (int g = 0; g < 4; ++g)
        Lm[w][rf * 16 + q * 4 + g] = accl[rf][g];
  }
  if (w >= 4) {
#pragma unroll
    for (int rf = 0; rf < 2; ++rf)
#pragma unroll
      for (int c = 0; c < 4; ++c)
#pragma unroll
        for (int g = 0; g < 4; ++g)
          MRG[w - 4][rf * 16 + q * 4 + g][c * 16 + lm] = acc[rf][c][g];
  }
  __syncthreads();
  if (w < 4) {
#pragma unroll
    for (int rf = 0; rf < 2; ++rf)
#pragma unroll
      for (int c = 0; c < 4; ++c)
#pragma unroll
        for (int g = 0; g < 4; ++g)
          acc[rf][c][g] += MRG[w][rf * 16 + q * 4 + g][c * 16 + lm];
  }
  __syncthreads();
  if (w >= 1 && w < 4) {
#pragma unroll
    for (int rf = 0; rf < 2; ++rf)
#pragma unroll
      for (int c = 0; c < 4; ++c)
#pragma unroll
        for (int g = 0; g < 4; ++g)
          MRG[w - 1][rf * 16 + q * 4 + g][c * 16 + lm] = acc[rf][c][g];
  }
  __syncthreads();
  if (w == 0) {
#pragma unroll
    for (int rf = 0; rf < 2; ++rf) {
#pragma unroll
      for (int g = 0; g < 4; ++g) {
        const int row = rf * 16 + q * 4 + g;
        float l = 0.f;
#pragma unroll
        for (int ww = 0; ww < 8; ++ww) l += Lm[ww][row];
        const float inv = 1.0f / l;
        const int grow = ib + row;
#pragma unroll
        for (int c = 0; c < 4; ++c) {
          const int col = c * 16 + lm;
          float v = acc[rf][c][g]
                  + MRG[0][row][col] + MRG[1][row][col] + MRG[2][row][col];
          float o = fmaf(v, inv, bias[h * 64 + col]);
          __builtin_nontemporal_store(fmaxf(o, 0.0f),
              out + (size_t)grow * 256 + h * 64 + col);
        }
      }
    }
  }
}

// ---------------------------------------------------------------------------
extern "C" void kernel_launch(void* const* d_in, const int* in_sizes, int n_in,
                              void* d_out, int out_size, void* d_ws, size_t ws_size,
                              hipStream_t stream) {
  const float* x    = (const float*)d_in[0];
  const int*   adj  = (const int*)d_in[1];
  const float* W    = (const float*)d_in[2];
  const float* a    = (const float*)d_in[3];
  const float* bias = (const float*)d_in[4];
  float* out = (float*)d_out;

  // ws: V2 2MB | bits 2MB | ssrc 64KB | sdst 64KB
  short* V2 = (short*)d_ws;
  unsigned long long* bits =
      (unsigned long long*)((char*)d_ws + (size_t)2 * 1024 * 1024);
  float* ssrc = (float*)((char*)d_ws + (size_t)4 * 1024 * 1024);
  float* sdst = ssrc + NH * NN;

  gat_pre<<<768, 512, 0, stream>>>(adj, x, W, a, bits, V2, ssrc, sdst);
  gat_k2<<<512, 512, 0, stream>>>((const unsigned*)bits, V2, ssrc, sdst, bias, out);
}